// Round 7
// baseline (283.949 us; speedup 1.0000x reference)
//
#include <hip/hip_runtime.h>
#include <math.h>

// GlobalSphereAttention: LN -> QKV -> per-head dots * scale * (1+sph)
//   -> cross-head mean/std(ddof=1) normalize -> softmax(j) -> PV -> out proj.
// B=2, N=2048, DIM=512, HEADS=8, DHEAD=64.
// Round 7: MFMA bf16 hi/lo GEMMs (qkv + out), attention K-prefetch, S=8 tier.

typedef __attribute__((ext_vector_type(8))) short bf16x8;
typedef __attribute__((ext_vector_type(8))) unsigned short u16x8;
typedef __attribute__((ext_vector_type(4))) float f32x4;

constexpr int kDim = 512;
constexpr int kN = 2048;
constexpr float kEps = 1e-5f;
constexpr float kScale = 0.125f; // 64^-0.5

// ws layout (byte offsets): 6 planes (24MB) + op partials (8MB each) + ml + mu/rs
constexpr size_t OFF_QHI  = 0;
constexpr size_t OFF_QLO  = 4u << 20;
constexpr size_t OFF_KHI  = 8u << 20;
constexpr size_t OFF_KLO  = 12u << 20;
constexpr size_t OFF_VTHI = 16u << 20;  // transposed [bh][d][n]
constexpr size_t OFF_VTLO = 20u << 20;
constexpr size_t OFF_OP   = 24u << 20;  // op_s = OP + s*8MB; op0 aliases VN
constexpr size_t OFF_VNHI = 24u << 20;  // natural V (dead after vtrans)
constexpr size_t OFF_VNLO = 28u << 20;
constexpr size_t OP_STRIDE = 2097152;   // floats per partial (8 MiB)

__device__ __forceinline__ void bf16_split(float x, unsigned short& hi,
                                           unsigned short& lo) {
  unsigned int u = __float_as_uint(x);
  hi = (unsigned short)(u >> 16);
  float r = x - __uint_as_float(u & 0xffff0000u);  // exact
  lo = (unsigned short)(__float_as_uint(r) >> 16);
}
__device__ __forceinline__ f32x4 mfma16(bf16x8 a, bf16x8 b, f32x4 c) {
  return __builtin_amdgcn_mfma_f32_16x16x32_bf16(a, b, c, 0, 0, 0);
}

// ---------------- K1: LayerNorm row stats ----------------
__global__ __launch_bounds__(256) void k_ln_stats(const float* __restrict__ x,
                                                  float* __restrict__ mu,
                                                  float* __restrict__ rs) {
  int row = blockIdx.x * 4 + (threadIdx.x >> 6);
  int lane = threadIdx.x & 63;
  const float4* xr = (const float4*)(x + (size_t)row * kDim + lane * 8);
  float4 a = xr[0], b = xr[1];
  float s = a.x + a.y + a.z + a.w + b.x + b.y + b.z + b.w;
  float q = a.x*a.x + a.y*a.y + a.z*a.z + a.w*a.w
          + b.x*b.x + b.y*b.y + b.z*b.z + b.w*b.w;
#pragma unroll
  for (int off = 32; off > 0; off >>= 1) {
    s += __shfl_down(s, off);
    q += __shfl_down(q, off);
  }
  if (lane == 0) {
    float m = s * (1.0f / kDim);
    float v = q * (1.0f / kDim) - m * m;
    mu[row] = m;
    rs[row] = 1.0f / sqrtf(v + kEps);
  }
}

// ---------------- K2: fused-LN QKV GEMM via MFMA (hi/lo 3-term) ------------
// [4096,512] x [512,1536]. Tile 128M x 64N, BK=32, 256 thr (4 waves).
__global__ __launch_bounds__(256, 3) void k_gemm_qkv(
    const float* __restrict__ x, const float* __restrict__ mu,
    const float* __restrict__ rs, const float* __restrict__ g,
    const float* __restrict__ bta, const float* __restrict__ w,
    unsigned short* __restrict__ qhi, unsigned short* __restrict__ qlo,
    unsigned short* __restrict__ khi, unsigned short* __restrict__ klo,
    unsigned short* __restrict__ vnhi, unsigned short* __restrict__ vnlo) {
  __shared__ unsigned short Ah[128 * 40], Al[128 * 40];  // [m][k], stride 40
  __shared__ unsigned short Bh[64 * 40], Bl[64 * 40];    // [n][k], stride 40
  const int t = threadIdx.x;
  const int wv = t >> 6;
  const int lane = t & 63;
  const int col = lane & 15, gq = lane >> 4;
  const int n0 = blockIdx.x * 64;
  const int m0 = blockIdx.y * 128;
  const int ar = t >> 1, aq = (t & 1) * 16;    // A-stage: row, k-offset
  const int bk = t >> 3, bn8 = (t & 7) * 8;    // B-stage: k-row, n-offset
  const float amu = mu[m0 + ar], ars = rs[m0 + ar];
  const float* xp = x + (size_t)(m0 + ar) * kDim;
  const float* wp = w + (size_t)bk * 1536 + n0 + bn8;

  f32x4 acc[2][4];
#pragma unroll
  for (int am = 0; am < 2; ++am)
#pragma unroll
    for (int bn = 0; bn < 4; ++bn) acc[am][bn] = (f32x4){0.f, 0.f, 0.f, 0.f};

  for (int k0 = 0; k0 < kDim; k0 += 32) {
    // ---- stage A (LN fused, split hi/lo) ----
#pragma unroll
    for (int half = 0; half < 2; ++half) {
      const int kk = k0 + aq + half * 8;
      float4 xa = *(const float4*)(xp + kk);
      float4 xb = *(const float4*)(xp + kk + 4);
      float4 ga = *(const float4*)(g + kk);
      float4 gb = *(const float4*)(g + kk + 4);
      float4 ba = *(const float4*)(bta + kk);
      float4 bb = *(const float4*)(bta + kk + 4);
      float e[8] = {(xa.x - amu) * ars * ga.x + ba.x,
                    (xa.y - amu) * ars * ga.y + ba.y,
                    (xa.z - amu) * ars * ga.z + ba.z,
                    (xa.w - amu) * ars * ga.w + ba.w,
                    (xb.x - amu) * ars * gb.x + bb.x,
                    (xb.y - amu) * ars * gb.y + bb.y,
                    (xb.z - amu) * ars * gb.z + bb.z,
                    (xb.w - amu) * ars * gb.w + bb.w};
      u16x8 vh, vl;
#pragma unroll
      for (int i = 0; i < 8; ++i) {
        unsigned short hi2, lo2;
        bf16_split(e[i], hi2, lo2);
        vh[i] = hi2;
        vl[i] = lo2;
      }
      *(u16x8*)&Ah[ar * 40 + aq + half * 8] = vh;
      *(u16x8*)&Al[ar * 40 + aq + half * 8] = vl;
    }
    // ---- stage B (split hi/lo, transpose to [n][k]) ----
    {
      float4 wa = *(const float4*)(wp + (size_t)k0 * 1536);
      float4 wb = *(const float4*)(wp + (size_t)k0 * 1536 + 4);
      float we[8] = {wa.x, wa.y, wa.z, wa.w, wb.x, wb.y, wb.z, wb.w};
#pragma unroll
      for (int i = 0; i < 8; ++i) {
        unsigned short hi2, lo2;
        bf16_split(we[i], hi2, lo2);
        Bh[(bn8 + i) * 40 + bk] = hi2;
        Bl[(bn8 + i) * 40 + bk] = lo2;
      }
    }
    __syncthreads();
    // ---- fragments + MFMA ----
    bf16x8 bhf[4], blf[4];
#pragma unroll
    for (int bn = 0; bn < 4; ++bn) {
      bhf[bn] = *(const bf16x8*)&Bh[(bn * 16 + col) * 40 + gq * 8];
      blf[bn] = *(const bf16x8*)&Bl[(bn * 16 + col) * 40 + gq * 8];
    }
#pragma unroll
    for (int am = 0; am < 2; ++am) {
      const int arow = wv * 32 + am * 16 + col;
      bf16x8 ahf = *(const bf16x8*)&Ah[arow * 40 + gq * 8];
      bf16x8 alf = *(const bf16x8*)&Al[arow * 40 + gq * 8];
#pragma unroll
      for (int bn = 0; bn < 4; ++bn) {
        f32x4 a = acc[am][bn];
        a = mfma16(ahf, bhf[bn], a);
        a = mfma16(alf, bhf[bn], a);
        a = mfma16(ahf, blf[bn], a);
        acc[am][bn] = a;
      }
    }
    __syncthreads();
  }
  // ---- epilogue: split planes scatter (q/k natural, v natural) ----
  const int which = n0 >> 9;
  const int hh = (n0 & 511) >> 6;
  unsigned short* ph = (which == 0) ? qhi : ((which == 1) ? khi : vnhi);
  unsigned short* pl = (which == 0) ? qlo : ((which == 1) ? klo : vnlo);
#pragma unroll
  for (int am = 0; am < 2; ++am) {
#pragma unroll
    for (int r = 0; r < 4; ++r) {
      const int m = m0 + wv * 32 + am * 16 + gq * 4 + r;
      const int bI = m >> 11, nn = m & 2047;
      const size_t base = ((size_t)(bI * 8 + hh) * kN + nn) * 64;
#pragma unroll
      for (int bn = 0; bn < 4; ++bn) {
        unsigned short hi2, lo2;
        bf16_split(acc[am][bn][r], hi2, lo2);
        ph[base + bn * 16 + col] = hi2;
        pl[base + bn * 16 + col] = lo2;
      }
    }
  }
}

// ---------------- K2b: V transpose [bh][n][64] -> [bh][d][n] ----------------
__global__ __launch_bounds__(256) void k_vtrans(
    const unsigned short* __restrict__ vnhi, const unsigned short* __restrict__ vnlo,
    unsigned short* __restrict__ vthi, unsigned short* __restrict__ vtlo) {
  __shared__ unsigned short tile[64][72];
  const int id = blockIdx.x;
  const int p = id >> 9;
  const int bh = (id >> 5) & 15;
  const int nt = id & 31;
  const unsigned short* src = (p ? vnlo : vnhi) + ((size_t)bh * kN + nt * 64) * 64;
  unsigned short* dst = (p ? vtlo : vthi) + (size_t)bh * 64 * kN + nt * 64;
  const int r = threadIdx.x >> 3;
  const int c = (threadIdx.x & 7) * 8;
#pragma unroll
  for (int rr = 0; rr < 64; rr += 32) {
    u16x8 v = *(const u16x8*)(src + (size_t)(r + rr) * 64 + c);
    *(u16x8*)&tile[r + rr][c] = v;
  }
  __syncthreads();
#pragma unroll
  for (int dd = 0; dd < 64; dd += 32) {
    int d = r + dd;
    u16x8 v;
#pragma unroll
    for (int e = 0; e < 8; ++e) v[e] = tile[c + e][d];
    *(u16x8*)(dst + (size_t)d * kN + c) = v;
  }
}

// ---------------- K3: fused sphere attention, Q-tile 64, K-prefetch --------
// grid = 64*S blocks x 512 threads (8 waves; wave=head; 4 row-blocks/wave).
__global__ __launch_bounds__(512, 2) void k_attn(
    const unsigned short* __restrict__ qhi, const unsigned short* __restrict__ qlo,
    const unsigned short* __restrict__ khi, const unsigned short* __restrict__ klo,
    const unsigned short* __restrict__ vthi, const unsigned short* __restrict__ vtlo,
    const float* __restrict__ sph, float* __restrict__ op,
    float2* __restrict__ ml, int jLen) {
  constexpr int SSTR = 33;            // dwords/row
  __shared__ float Ss[512 * SSTR];    // 67.6 KB: row = h*64 + i (i in 0..63)

  const int t = threadIdx.x;
  const int h = t >> 6;
  const int lane = t & 63;
  const int col = lane & 15;
  const int g = lane >> 4;
  const int tileId = blockIdx.x & 63;
  const int sId = blockIdx.x >> 6;
  const int bI = tileId >> 5;
  const int i0 = (tileId & 31) << 6;
  const int jStart = sId * jLen;
  const int jEnd = (jStart + jLen < kN) ? (jStart + jLen) : kN;
  const size_t bh = (size_t)bI * 8 + h;
  float* opart = op + (size_t)sId * OP_STRIDE;

  // persistent Q fragments: 4 row-blocks x 2 d-chunks x hi/lo
  bf16x8 qhf[4][2], qlf[4][2];
#pragma unroll
  for (int rb = 0; rb < 4; ++rb) {
    const size_t qoff = (bh * kN + i0 + rb * 16 + col) * 64 + g * 8;
    qhf[rb][0] = *(const bf16x8*)(qhi + qoff);
    qhf[rb][1] = *(const bf16x8*)(qhi + qoff + 32);
    qlf[rb][0] = *(const bf16x8*)(qlo + qoff);
    qlf[rb][1] = *(const bf16x8*)(qlo + qoff + 32);
  }
  const unsigned short* kb_h = khi + (bh * kN + col) * 64 + g * 8;
  const unsigned short* kb_l = klo + (bh * kN + col) * 64 + g * 8;
  const unsigned short* vb_h = vthi + (bh * 64 + col) * kN + g * 8;
  const unsigned short* vb_l = vtlo + (bh * 64 + col) * kN + g * 8;

  // norm-phase ownership: thread -> (row iN, 4 j's at jN)
  const int iN = t >> 3;
  const int jN = (t & 7) * 4;
  const float* sphp = sph + (size_t)(i0 + iN) * kN + jN;
  float4 sphc = *(const float4*)(sphp + jStart);

  f32x4 oacc[4][4];
#pragma unroll
  for (int rb = 0; rb < 4; ++rb)
#pragma unroll
    for (int nf = 0; nf < 4; ++nf) oacc[rb][nf] = (f32x4){0.f, 0.f, 0.f, 0.f};
  float mreg[4] = {-INFINITY, -INFINITY, -INFINITY, -INFINITY};
  float lreg[4] = {0.f, 0.f, 0.f, 0.f};

  // K fragments for the first tile (prefetched into registers)
  bf16x8 kh[2][2], kl[2][2];
  {
    const size_t ko = (size_t)jStart * 64;
#pragma unroll
    for (int jf = 0; jf < 2; ++jf)
#pragma unroll
      for (int c = 0; c < 2; ++c) {
        kh[jf][c] = *(const bf16x8*)(kb_h + ko + jf * 1024 + c * 32);
        kl[jf][c] = *(const bf16x8*)(kb_l + ko + jf * 1024 + c * 32);
      }
  }

  for (int j0 = jStart; j0 < jEnd; j0 += 32) {
    // ---- A: QK^T, 4 row-blocks share the prefetched K-tile ----
#pragma unroll
    for (int rb = 0; rb < 4; ++rb)
#pragma unroll
      for (int jf = 0; jf < 2; ++jf) {
        f32x4 a = (f32x4){0.f, 0.f, 0.f, 0.f};
        a = mfma16(qhf[rb][0], kh[jf][0], a);
        a = mfma16(qhf[rb][1], kh[jf][1], a);
        a = mfma16(qlf[rb][0], kh[jf][0], a);
        a = mfma16(qlf[rb][1], kh[jf][1], a);
        a = mfma16(qhf[rb][0], kl[jf][0], a);
        a = mfma16(qhf[rb][1], kl[jf][1], a);
#pragma unroll
        for (int r = 0; r < 4; ++r)
          Ss[(h * 64 + rb * 16 + g * 4 + r) * SSTR + jf * 16 + col] = a[r];
      }
    // ---- issue V loads (consumed in D, covered by B+C) ----
    bf16x8 vhf[4], vlf[4];
#pragma unroll
    for (int nf = 0; nf < 4; ++nf) {
      vhf[nf] = *(const bf16x8*)(vb_h + (size_t)(nf * 16) * kN + j0);
      vlf[nf] = *(const bf16x8*)(vb_l + (size_t)(nf * 16) * kN + j0);
    }
    // ---- prefetch next K tile (consumed next iteration) ----
    {
      const int jp = (j0 + 32 < jEnd) ? (j0 + 32) : j0;
      const size_t ko = (size_t)jp * 64;
#pragma unroll
      for (int jf = 0; jf < 2; ++jf)
#pragma unroll
        for (int c = 0; c < 2; ++c) {
          kh[jf][c] = *(const bf16x8*)(kb_h + ko + jf * 1024 + c * 32);
          kl[jf][c] = *(const bf16x8*)(kb_l + ko + jf * 1024 + c * 32);
        }
    }
    __syncthreads();
    // ---- B: cross-head normalization (4 (i,j) per thread, vectorized) ----
    {
      const int jn = (j0 + 32 < jEnd) ? (j0 + 32) : j0;
      const float4 sphn = *(const float4*)(sphp + jn);  // prefetch next
      const float m4[4] = {kScale * (1.0f + sphc.x), kScale * (1.0f + sphc.y),
                           kScale * (1.0f + sphc.z), kScale * (1.0f + sphc.w)};
      float dv[8][4];
#pragma unroll
      for (int hh = 0; hh < 8; ++hh) {
        float4 v = *(const float4*)&Ss[(hh * 64 + iN) * SSTR + jN];
        dv[hh][0] = v.x * m4[0]; dv[hh][1] = v.y * m4[1];
        dv[hh][2] = v.z * m4[2]; dv[hh][3] = v.w * m4[3];
      }
#pragma unroll
      for (int jj = 0; jj < 4; ++jj) {
        float s = 0.f;
#pragma unroll
        for (int hh = 0; hh < 8; ++hh) s += dv[hh][jj];
        const float mean = s * 0.125f;
        float var = 0.f;
#pragma unroll
        for (int hh = 0; hh < 8; ++hh) {
          float d = dv[hh][jj] - mean;
          var += d * d;
        }
        const float inv = rsqrtf(var * (1.0f / 7.0f));
#pragma unroll
        for (int hh = 0; hh < 8; ++hh) dv[hh][jj] = (dv[hh][jj] - mean) * inv;
      }
#pragma unroll
      for (int hh = 0; hh < 8; ++hh) {
        float4 v = make_float4(dv[hh][0], dv[hh][1], dv[hh][2], dv[hh][3]);
        *(float4*)&Ss[(hh * 64 + iN) * SSTR + jN] = v;
      }
      sphc = sphn;
    }
    __syncthreads();
    // ---- C: online softmax per row-block; P packed to registers ----
    bf16x8 ph[4], pl[4];
    float fx[4];
#pragma unroll
    for (int rb = 0; rb < 4; ++rb) {
      const float* srow = &Ss[(h * 64 + rb * 16 + col) * SSTR + g * 8];
      float4 v0 = *(const float4*)(srow);
      float4 v1 = *(const float4*)(srow + 4);
      float vals[8] = {v0.x, v0.y, v0.z, v0.w, v1.x, v1.y, v1.z, v1.w};
      float mx = vals[0];
#pragma unroll
      for (int q = 1; q < 8; ++q) mx = fmaxf(mx, vals[q]);
      mx = fmaxf(mx, __shfl_xor(mx, 16));
      mx = fmaxf(mx, __shfl_xor(mx, 32));
      const float Mn = fmaxf(mreg[rb], mx);
      const float f = __expf(mreg[rb] - Mn);
      float s = 0.f;
      float pv[8];
#pragma unroll
      for (int q = 0; q < 8; ++q) {
        pv[q] = __expf(vals[q] - Mn);
        s += pv[q];
      }
      s += __shfl_xor(s, 16);
      s += __shfl_xor(s, 32);
      lreg[rb] = lreg[rb] * f + s;
      mreg[rb] = Mn;
      fx[rb] = f;
#pragma unroll
      for (int q = 0; q < 8; ++q) {
        unsigned short hi2, lo2;
        bf16_split(pv[q], hi2, lo2);
        ph[rb][q] = (short)hi2;
        pl[rb][q] = (short)lo2;
      }
    }
    // ---- D: PV, 4 row-blocks share one V-tile (no barrier; regs only) ----
#pragma unroll
    for (int rb = 0; rb < 4; ++rb) {
      float fr[4];
#pragma unroll
      for (int r = 0; r < 4; ++r) fr[r] = __shfl(fx[rb], g * 4 + r);
#pragma unroll
      for (int nf = 0; nf < 4; ++nf) {
        f32x4 a = oacc[rb][nf];
#pragma unroll
        for (int r = 0; r < 4; ++r) a[r] *= fr[r];
        a = mfma16(ph[rb], vhf[nf], a);
        a = mfma16(pl[rb], vhf[nf], a);
        a = mfma16(ph[rb], vlf[nf], a);
        oacc[rb][nf] = a;
      }
    }
  }
  // ---- epilogue: (m,l) + unnormalized O ----
#pragma unroll
  for (int rb = 0; rb < 4; ++rb) {
    if (g == 0)
      ml[((size_t)sId * 16 + bh) * kN + (i0 + rb * 16 + col)] =
          make_float2(mreg[rb], lreg[rb]);
#pragma unroll
    for (int r = 0; r < 4; ++r) {
      float* dst = opart + ((size_t)bI * kN + i0 + rb * 16 + g * 4 + r) * 512 + h * 64;
#pragma unroll
      for (int nf = 0; nf < 4; ++nf)
        dst[nf * 16 + col] = oacc[rb][nf][r];
    }
  }
}

// ---------------- K3b: combine split partials in place into op0 ----------------
__global__ __launch_bounds__(256) void k_combine(float* __restrict__ op,
    const float2* __restrict__ ml, int S) {
  const size_t e = ((size_t)blockIdx.x * 256 + threadIdx.x) * 4;
  const int row = (int)(e >> 9);
  const int col = (int)(e & 511);
  const int h = col >> 6;
  const int bI = row >> 11;
  const int n = row & 2047;
  const size_t mlBase = (size_t)(bI * 8 + h) * kN + n;
  float ms = -INFINITY;
  for (int s = 0; s < S; ++s)
    ms = fmaxf(ms, ml[(size_t)s * 16 * kN + mlBase].x);
  float L = 0.f;
  float4 acc = make_float4(0.f, 0.f, 0.f, 0.f);
  for (int s = 0; s < S; ++s) {
    float2 v = ml[(size_t)s * 16 * kN + mlBase];
    float wgt = __expf(v.x - ms);
    L += v.y * wgt;
    float4 o4 = *(const float4*)(op + (size_t)s * OP_STRIDE + e);
    acc.x += o4.x * wgt; acc.y += o4.y * wgt;
    acc.z += o4.z * wgt; acc.w += o4.w * wgt;
  }
  float inv = 1.0f / L;
  *(float4*)(op + e) = make_float4(acc.x * inv, acc.y * inv,
                                   acc.z * inv, acc.w * inv);
}

// ---------------- K4: out projection via MFMA [4096,512]x[512,512] + bias --
__global__ __launch_bounds__(256, 3) void k_gemm_out(
    const float* __restrict__ a, const float* __restrict__ w,
    const float* __restrict__ bias, float* __restrict__ out) {
  __shared__ unsigned short Ah[128 * 40], Al[128 * 40];
  __shared__ unsigned short Bh[64 * 40], Bl[64 * 40];
  const int t = threadIdx.x;
  const int wv = t >> 6;
  const int lane = t & 63;
  const int col = lane & 15, gq = lane >> 4;
  const int n0 = blockIdx.x * 64;
  const int m0 = blockIdx.y * 128;
  const int ar = t >> 1, aq = (t & 1) * 16;
  const int bk = t >> 3, bn8 = (t & 7) * 8;
  const float* ap = a + (size_t)(m0 + ar) * 512;
  const float* wp = w + (size_t)bk * 512 + n0 + bn8;

  f32x4 acc[2][4];
#pragma unroll
  for (int am = 0; am < 2; ++am)
#pragma unroll
    for (int bn = 0; bn < 4; ++bn) acc[am][bn] = (f32x4){0.f, 0.f, 0.f, 0.f};

  for (int k0 = 0; k0 < 512; k0 += 32) {
#pragma unroll
    for (int half = 0; half < 2; ++half) {
      const int kk = k0 + aq + half * 8;
      float4 xa = *(const float4*)(ap + kk);
      float4 xb = *(const float4*)(ap + kk + 4);
      float e[8] = {xa.x, xa.y, xa.z, xa.w, xb.x, xb.y, xb.z, xb.w};
      u16x8 vh, vl;
#pragma unroll
      for (int i = 0; i < 8; ++i) {
        unsigned short hi2, lo2;
        bf16_split(e[i], hi2, lo2);
        vh[i] = hi2;
        vl[i] = lo2;
      }
      *(u16x8*)&Ah[ar * 40 + aq + half * 8] = vh;
      *(u16x8*)&Al[ar * 40 + aq + half * 8] = vl;
    }
    {
      float4 wa = *(const float4*)(wp + (size_t)k0 * 512);
      float4 wb = *(const float4*)(wp + (size_t)k0 * 512 + 4);
      float we[8] = {wa.x, wa.y, wa.z, wa.w, wb.x, wb.y, wb.z, wb.w};
#pragma unroll
      for (int i = 0; i < 8; ++i) {
        unsigned short hi2, lo2;
        bf16_split(we[i], hi2, lo2);
        Bh[(bn8 + i) * 40 + bk] = hi2;
        Bl[(bn8 + i) * 40 + bk] = lo2;
      }
    }
    __syncthreads();
    bf16x8 bhf[4], blf[4];
#pragma unroll
    for (int bn = 0; bn < 4; ++bn) {
      bhf[bn] = *(const bf16x8*)&Bh[(bn * 16 + col) * 40 + gq * 8];
      blf[bn] = *(const bf16x8*)&Bl[(bn * 16 + col) * 40 + gq * 8];
    }
#pragma unroll
    for (int am = 0; am < 2; ++am) {
      const int arow = wv * 32 + am * 16 + col;
      bf16x8 ahf = *(const bf16x8*)&Ah[arow * 40 + gq * 8];
      bf16x8 alf = *(const bf16x8*)&Al[arow * 40 + gq * 8];
#pragma unroll
      for (int bn = 0; bn < 4; ++bn) {
        f32x4 aa = acc[am][bn];
        aa = mfma16(ahf, bhf[bn], aa);
        aa = mfma16(alf, bhf[bn], aa);
        aa = mfma16(ahf, blf[bn], aa);
        acc[am][bn] = aa;
      }
    }
    __syncthreads();
  }
  float bv[4];
#pragma unroll
  for (int bn = 0; bn < 4; ++bn) bv[bn] = bias[n0 + bn * 16 + col];
#pragma unroll
  for (int am = 0; am < 2; ++am) {
#pragma unroll
    for (int r = 0; r < 4; ++r) {
      const int m = m0 + wv * 32 + am * 16 + gq * 4 + r;
#pragma unroll
      for (int bn = 0; bn < 4; ++bn)
        out[(size_t)m * 512 + n0 + bn * 16 + col] = acc[am][bn][r] + bv[bn];
    }
  }
}

extern "C" void kernel_launch(void* const* d_in, const int* in_sizes, int n_in,
                              void* d_out, int out_size, void* d_ws, size_t ws_size,
                              hipStream_t stream) {
  (void)in_sizes; (void)n_in; (void)out_size;
  const float* x    = (const float*)d_in[0];
  const float* sph  = (const float*)d_in[1];
  const float* g    = (const float*)d_in[2];
  const float* bta  = (const float*)d_in[3];
  const float* wqkv = (const float*)d_in[4];
  const float* wout = (const float*)d_in[5];
  const float* bout = (const float*)d_in[6];
  float* out = (float*)d_out;
  char* ws = (char*)d_ws;

  unsigned short* qhi  = (unsigned short*)(ws + OFF_QHI);
  unsigned short* qlo  = (unsigned short*)(ws + OFF_QLO);
  unsigned short* khi  = (unsigned short*)(ws + OFF_KHI);
  unsigned short* klo  = (unsigned short*)(ws + OFF_KLO);
  unsigned short* vthi = (unsigned short*)(ws + OFF_VTHI);
  unsigned short* vtlo = (unsigned short*)(ws + OFF_VTLO);
  unsigned short* vnhi = (unsigned short*)(ws + OFF_VNHI);
  unsigned short* vnlo = (unsigned short*)(ws + OFF_VNLO);
  float* op = (float*)(ws + OFF_OP);

  // split count by available ws: need 24MB planes + S*8MB + S*256KB + 64KB
  int S, jLen;
  if      (ws_size >= (96u << 20)) { S = 8; jLen = 256;  }
  else if (ws_size >= (59u << 20)) { S = 4; jLen = 512;  }
  else if (ws_size >= (51u << 20)) { S = 3; jLen = 704;  }
  else if (ws_size >= (43u << 20)) { S = 2; jLen = 1024; }
  else                             { S = 1; jLen = 2048; }
  float2* ml = (float2*)(ws + OFF_OP + (size_t)S * OP_STRIDE * 4);
  float* mu  = (float*)((char*)ml + (size_t)S * 16 * kN * 8);
  float* rs  = mu + 4096;

  k_ln_stats<<<dim3(1024), dim3(256), 0, stream>>>(x, mu, rs);
  k_gemm_qkv<<<dim3(24, 32), dim3(256), 0, stream>>>(x, mu, rs, g, bta, wqkv,
                                                     qhi, qlo, khi, klo, vnhi, vnlo);
  k_vtrans<<<dim3(1024), dim3(256), 0, stream>>>(vnhi, vnlo, vthi, vtlo);
  k_attn<<<dim3(64 * S), dim3(512), 0, stream>>>(qhi, qlo, khi, klo, vthi, vtlo,
                                                 sph, op, ml, jLen);
  k_combine<<<dim3(2048), dim3(256), 0, stream>>>(op, ml, S);
  k_gemm_out<<<dim3(8, 32), dim3(256), 0, stream>>>(op, wout, bout, out);
}

// Round 8
// 186.474 us; speedup vs baseline: 1.5227x; 1.5227x over previous
//
#include <hip/hip_runtime.h>
#include <math.h>

// GlobalSphereAttention: LN -> QKV -> per-head dots * scale * (1+sph)
//   -> cross-head mean/std(ddof=1) normalize -> softmax(j) -> PV -> out proj.
// B=2, N=2048, DIM=512, HEADS=8, DHEAD=64.
// Round 8: slim bf16. K/V/P single-plane bf16 (error cancels through softmax:
// dout ~ drel*sqrt(sum p^2) ~ 1e-4), Q hi/lo, out-proj 3-term hi/lo.
// QKV GEMM plain bf16. S<=4 (S=8 added Q/O traffic, hurt). K-prefetch kept.

typedef __attribute__((ext_vector_type(8))) short bf16x8;
typedef __attribute__((ext_vector_type(8))) unsigned short u16x8;
typedef __attribute__((ext_vector_type(4))) float f32x4;

constexpr int kDim = 512;
constexpr int kN = 2048;
constexpr float kEps = 1e-5f;
constexpr float kScale = 0.125f; // 64^-0.5

// ws layout (byte offsets), compact: 4 live planes (16MB) + VN (4MB, dead
// after vtrans) + op partials (8MB each) + ml + mu/rs
constexpr size_t OFF_QHI  = 0;
constexpr size_t OFF_QLO  = 4u << 20;
constexpr size_t OFF_KHI  = 8u << 20;
constexpr size_t OFF_VTHI = 12u << 20;  // transposed [bh][d][n]
constexpr size_t OFF_VNHI = 16u << 20;  // natural [bh][n][d] (dead after vtrans)
constexpr size_t OFF_OP   = 20u << 20;
constexpr size_t OP_STRIDE = 2097152;   // floats per partial (8 MiB)

__device__ __forceinline__ unsigned short bf16_rne(float f) {
  unsigned int u = __float_as_uint(f);
  u += 0x7fffu + ((u >> 16) & 1u);
  return (unsigned short)(u >> 16);
}
__device__ __forceinline__ void bf16_split(float x, unsigned short& hi,
                                           unsigned short& lo) {
  unsigned int u = __float_as_uint(x);
  hi = (unsigned short)(u >> 16);
  float r = x - __uint_as_float(u & 0xffff0000u);  // exact
  lo = (unsigned short)(__float_as_uint(r) >> 16);
}
__device__ __forceinline__ f32x4 mfma16(bf16x8 a, bf16x8 b, f32x4 c) {
  return __builtin_amdgcn_mfma_f32_16x16x32_bf16(a, b, c, 0, 0, 0);
}

// ---------------- K1: LayerNorm row stats ----------------
__global__ __launch_bounds__(256) void k_ln_stats(const float* __restrict__ x,
                                                  float* __restrict__ mu,
                                                  float* __restrict__ rs) {
  int row = blockIdx.x * 4 + (threadIdx.x >> 6);
  int lane = threadIdx.x & 63;
  const float4* xr = (const float4*)(x + (size_t)row * kDim + lane * 8);
  float4 a = xr[0], b = xr[1];
  float s = a.x + a.y + a.z + a.w + b.x + b.y + b.z + b.w;
  float q = a.x*a.x + a.y*a.y + a.z*a.z + a.w*a.w
          + b.x*b.x + b.y*b.y + b.z*b.z + b.w*b.w;
#pragma unroll
  for (int off = 32; off > 0; off >>= 1) {
    s += __shfl_down(s, off);
    q += __shfl_down(q, off);
  }
  if (lane == 0) {
    float m = s * (1.0f / kDim);
    float v = q * (1.0f / kDim) - m * m;
    mu[row] = m;
    rs[row] = 1.0f / sqrtf(v + kEps);
  }
}

// ---------------- K2: fused-LN QKV GEMM via MFMA (plain bf16) --------------
// [4096,512] x [512,1536]. Tile 128M x 64N, BK=32, 256 thr (4 waves).
__global__ __launch_bounds__(256, 3) void k_gemm_qkv(
    const float* __restrict__ x, const float* __restrict__ mu,
    const float* __restrict__ rs, const float* __restrict__ g,
    const float* __restrict__ bta, const float* __restrict__ w,
    unsigned short* __restrict__ qhi, unsigned short* __restrict__ qlo,
    unsigned short* __restrict__ khi, unsigned short* __restrict__ vnhi) {
  __shared__ unsigned short Ah[128 * 40];  // [m][k], stride 40
  __shared__ unsigned short Bh[64 * 40];   // [n][k], stride 40
  const int t = threadIdx.x;
  const int wv = t >> 6;
  const int lane = t & 63;
  const int col = lane & 15, gq = lane >> 4;
  const int n0 = blockIdx.x * 64;
  const int m0 = blockIdx.y * 128;
  const int ar = t >> 1, aq = (t & 1) * 16;    // A-stage: row, k-offset
  const int bk = t >> 3, bn8 = (t & 7) * 8;    // B-stage: k-row, n-offset
  const float amu = mu[m0 + ar], ars = rs[m0 + ar];
  const float* xp = x + (size_t)(m0 + ar) * kDim;
  const float* wp = w + (size_t)bk * 1536 + n0 + bn8;

  f32x4 acc[2][4];
#pragma unroll
  for (int am = 0; am < 2; ++am)
#pragma unroll
    for (int bn = 0; bn < 4; ++bn) acc[am][bn] = (f32x4){0.f, 0.f, 0.f, 0.f};

  for (int k0 = 0; k0 < kDim; k0 += 32) {
    // ---- stage A (LN fused, bf16 rne) ----
#pragma unroll
    for (int half = 0; half < 2; ++half) {
      const int kk = k0 + aq + half * 8;
      float4 xa = *(const float4*)(xp + kk);
      float4 xb = *(const float4*)(xp + kk + 4);
      float4 ga = *(const float4*)(g + kk);
      float4 gb = *(const float4*)(g + kk + 4);
      float4 ba = *(const float4*)(bta + kk);
      float4 bb = *(const float4*)(bta + kk + 4);
      float e[8] = {(xa.x - amu) * ars * ga.x + ba.x,
                    (xa.y - amu) * ars * ga.y + ba.y,
                    (xa.z - amu) * ars * ga.z + ba.z,
                    (xa.w - amu) * ars * ga.w + ba.w,
                    (xb.x - amu) * ars * gb.x + bb.x,
                    (xb.y - amu) * ars * gb.y + bb.y,
                    (xb.z - amu) * ars * gb.z + bb.z,
                    (xb.w - amu) * ars * gb.w + bb.w};
      u16x8 vh;
#pragma unroll
      for (int i = 0; i < 8; ++i) vh[i] = bf16_rne(e[i]);
      *(u16x8*)&Ah[ar * 40 + aq + half * 8] = vh;
    }
    // ---- stage B (bf16 rne, transpose to [n][k]) ----
    {
      float4 wa = *(const float4*)(wp + (size_t)k0 * 1536);
      float4 wb = *(const float4*)(wp + (size_t)k0 * 1536 + 4);
      float we[8] = {wa.x, wa.y, wa.z, wa.w, wb.x, wb.y, wb.z, wb.w};
#pragma unroll
      for (int i = 0; i < 8; ++i)
        Bh[(bn8 + i) * 40 + bk] = bf16_rne(we[i]);
    }
    __syncthreads();
    // ---- fragments + MFMA ----
    bf16x8 bhf[4];
#pragma unroll
    for (int bn = 0; bn < 4; ++bn)
      bhf[bn] = *(const bf16x8*)&Bh[(bn * 16 + col) * 40 + gq * 8];
#pragma unroll
    for (int am = 0; am < 2; ++am) {
      const int arow = wv * 32 + am * 16 + col;
      bf16x8 ahf = *(const bf16x8*)&Ah[arow * 40 + gq * 8];
#pragma unroll
      for (int bn = 0; bn < 4; ++bn)
        acc[am][bn] = mfma16(ahf, bhf[bn], acc[am][bn]);
    }
    __syncthreads();
  }
  // ---- epilogue: q -> hi/lo planes; k,v -> single bf16 plane ----
  const int which = n0 >> 9;
  const int hh = (n0 & 511) >> 6;
#pragma unroll
  for (int am = 0; am < 2; ++am) {
#pragma unroll
    for (int r = 0; r < 4; ++r) {
      const int m = m0 + wv * 32 + am * 16 + gq * 4 + r;
      const int bI = m >> 11, nn = m & 2047;
      const size_t base = ((size_t)(bI * 8 + hh) * kN + nn) * 64;
      if (which == 0) {
#pragma unroll
        for (int bn = 0; bn < 4; ++bn) {
          unsigned short hi2, lo2;
          bf16_split(acc[am][bn][r], hi2, lo2);
          qhi[base + bn * 16 + col] = hi2;
          qlo[base + bn * 16 + col] = lo2;
        }
      } else {
        unsigned short* p = (which == 1) ? khi : vnhi;
#pragma unroll
        for (int bn = 0; bn < 4; ++bn)
          p[base + bn * 16 + col] = bf16_rne(acc[am][bn][r]);
      }
    }
  }
}

// ---------------- K2b: V transpose [bh][n][64] -> [bh][d][n] ----------------
__global__ __launch_bounds__(256) void k_vtrans(
    const unsigned short* __restrict__ vnhi, unsigned short* __restrict__ vthi) {
  __shared__ unsigned short tile[64][72];
  const int id = blockIdx.x;
  const int bh = id >> 5;
  const int nt = id & 31;
  const unsigned short* src = vnhi + ((size_t)bh * kN + nt * 64) * 64;
  unsigned short* dst = vthi + (size_t)bh * 64 * kN + nt * 64;
  const int r = threadIdx.x >> 3;
  const int c = (threadIdx.x & 7) * 8;
#pragma unroll
  for (int rr = 0; rr < 64; rr += 32) {
    u16x8 v = *(const u16x8*)(src + (size_t)(r + rr) * 64 + c);
    *(u16x8*)&tile[r + rr][c] = v;
  }
  __syncthreads();
#pragma unroll
  for (int dd = 0; dd < 64; dd += 32) {
    int d = r + dd;
    u16x8 v;
#pragma unroll
    for (int e = 0; e < 8; ++e) v[e] = tile[c + e][d];
    *(u16x8*)(dst + (size_t)d * kN + c) = v;
  }
}

// ---------------- K3: fused sphere attention, Q-tile 64, slim bf16 ---------
// grid = 64*S blocks x 512 threads (8 waves; wave=head; 4 row-blocks/wave).
__global__ __launch_bounds__(512, 2) void k_attn(
    const unsigned short* __restrict__ qhi, const unsigned short* __restrict__ qlo,
    const unsigned short* __restrict__ khi, const unsigned short* __restrict__ vthi,
    const float* __restrict__ sph, float* __restrict__ op,
    float2* __restrict__ ml, int jLen) {
  constexpr int SSTR = 33;            // dwords/row
  __shared__ float Ss[512 * SSTR];    // 67.6 KB: row = h*64 + i (i in 0..63)

  const int t = threadIdx.x;
  const int h = t >> 6;
  const int lane = t & 63;
  const int col = lane & 15;
  const int g = lane >> 4;
  const int tileId = blockIdx.x & 63;
  const int sId = blockIdx.x >> 6;
  const int bI = tileId >> 5;
  const int i0 = (tileId & 31) << 6;
  const int jStart = sId * jLen;
  const int jEnd = (jStart + jLen < kN) ? (jStart + jLen) : kN;
  const size_t bh = (size_t)bI * 8 + h;
  float* opart = op + (size_t)sId * OP_STRIDE;

  // persistent Q fragments: 4 row-blocks x 2 d-chunks x hi/lo
  bf16x8 qhf[4][2], qlf[4][2];
#pragma unroll
  for (int rb = 0; rb < 4; ++rb) {
    const size_t qoff = (bh * kN + i0 + rb * 16 + col) * 64 + g * 8;
    qhf[rb][0] = *(const bf16x8*)(qhi + qoff);
    qhf[rb][1] = *(const bf16x8*)(qhi + qoff + 32);
    qlf[rb][0] = *(const bf16x8*)(qlo + qoff);
    qlf[rb][1] = *(const bf16x8*)(qlo + qoff + 32);
  }
  const unsigned short* kb_h = khi + (bh * kN + col) * 64 + g * 8;
  const unsigned short* vb_h = vthi + (bh * 64 + col) * kN + g * 8;

  // norm-phase ownership: thread -> (row iN, 4 j's at jN)
  const int iN = t >> 3;
  const int jN = (t & 7) * 4;
  const float* sphp = sph + (size_t)(i0 + iN) * kN + jN;
  float4 sphc = *(const float4*)(sphp + jStart);

  f32x4 oacc[4][4];
#pragma unroll
  for (int rb = 0; rb < 4; ++rb)
#pragma unroll
    for (int nf = 0; nf < 4; ++nf) oacc[rb][nf] = (f32x4){0.f, 0.f, 0.f, 0.f};
  float mreg[4] = {-INFINITY, -INFINITY, -INFINITY, -INFINITY};
  float lreg[4] = {0.f, 0.f, 0.f, 0.f};

  // K fragments for the first tile (prefetched into registers)
  bf16x8 kh[2][2];
  {
    const size_t ko = (size_t)jStart * 64;
#pragma unroll
    for (int jf = 0; jf < 2; ++jf)
#pragma unroll
      for (int c = 0; c < 2; ++c)
        kh[jf][c] = *(const bf16x8*)(kb_h + ko + jf * 1024 + c * 32);
  }

  for (int j0 = jStart; j0 < jEnd; j0 += 32) {
    // ---- A: QK^T, 4 row-blocks share the prefetched K-tile ----
#pragma unroll
    for (int rb = 0; rb < 4; ++rb)
#pragma unroll
      for (int jf = 0; jf < 2; ++jf) {
        f32x4 a = (f32x4){0.f, 0.f, 0.f, 0.f};
        a = mfma16(qhf[rb][0], kh[jf][0], a);
        a = mfma16(qhf[rb][1], kh[jf][1], a);
        a = mfma16(qlf[rb][0], kh[jf][0], a);
        a = mfma16(qlf[rb][1], kh[jf][1], a);
#pragma unroll
        for (int r = 0; r < 4; ++r)
          Ss[(h * 64 + rb * 16 + g * 4 + r) * SSTR + jf * 16 + col] = a[r];
      }
    // ---- issue V loads (consumed in D, covered by B+C) ----
    bf16x8 vhf[4];
#pragma unroll
    for (int nf = 0; nf < 4; ++nf)
      vhf[nf] = *(const bf16x8*)(vb_h + (size_t)(nf * 16) * kN + j0);
    // ---- prefetch next K tile (consumed next iteration) ----
    {
      const int jp = (j0 + 32 < jEnd) ? (j0 + 32) : j0;
      const size_t ko = (size_t)jp * 64;
#pragma unroll
      for (int jf = 0; jf < 2; ++jf)
#pragma unroll
        for (int c = 0; c < 2; ++c)
          kh[jf][c] = *(const bf16x8*)(kb_h + ko + jf * 1024 + c * 32);
    }
    __syncthreads();
    // ---- B: cross-head normalization (4 (i,j) per thread, vectorized) ----
    {
      const int jn = (j0 + 32 < jEnd) ? (j0 + 32) : j0;
      const float4 sphn = *(const float4*)(sphp + jn);  // prefetch next
      const float m4[4] = {kScale * (1.0f + sphc.x), kScale * (1.0f + sphc.y),
                           kScale * (1.0f + sphc.z), kScale * (1.0f + sphc.w)};
      float dv[8][4];
#pragma unroll
      for (int hh = 0; hh < 8; ++hh) {
        float4 v = *(const float4*)&Ss[(hh * 64 + iN) * SSTR + jN];
        dv[hh][0] = v.x * m4[0]; dv[hh][1] = v.y * m4[1];
        dv[hh][2] = v.z * m4[2]; dv[hh][3] = v.w * m4[3];
      }
#pragma unroll
      for (int jj = 0; jj < 4; ++jj) {
        float s = 0.f;
#pragma unroll
        for (int hh = 0; hh < 8; ++hh) s += dv[hh][jj];
        const float mean = s * 0.125f;
        float var = 0.f;
#pragma unroll
        for (int hh = 0; hh < 8; ++hh) {
          float d = dv[hh][jj] - mean;
          var += d * d;
        }
        const float inv = rsqrtf(var * (1.0f / 7.0f));
#pragma unroll
        for (int hh = 0; hh < 8; ++hh) dv[hh][jj] = (dv[hh][jj] - mean) * inv;
      }
#pragma unroll
      for (int hh = 0; hh < 8; ++hh) {
        float4 v = make_float4(dv[hh][0], dv[hh][1], dv[hh][2], dv[hh][3]);
        *(float4*)&Ss[(hh * 64 + iN) * SSTR + jN] = v;
      }
      sphc = sphn;
    }
    __syncthreads();
    // ---- C: online softmax per row-block; P packed (bf16 rne) ----
    bf16x8 ph[4];
    float fx[4];
#pragma unroll
    for (int rb = 0; rb < 4; ++rb) {
      const float* srow = &Ss[(h * 64 + rb * 16 + col) * SSTR + g * 8];
      float4 v0 = *(const float4*)(srow);
      float4 v1 = *(const float4*)(srow + 4);
      float vals[8] = {v0.x, v0.y, v0.z, v0.w, v1.x, v1.y, v1.z, v1.w};
      float mx = vals[0];
#pragma unroll
      for (int q = 1; q < 8; ++q) mx = fmaxf(mx, vals[q]);
      mx = fmaxf(mx, __shfl_xor(mx, 16));
      mx = fmaxf(mx, __shfl_xor(mx, 32));
      const float Mn = fmaxf(mreg[rb], mx);
      const float f = __expf(mreg[rb] - Mn);
      float s = 0.f;
      float pv[8];
#pragma unroll
      for (int q = 0; q < 8; ++q) {
        pv[q] = __expf(vals[q] - Mn);
        s += pv[q];
      }
      s += __shfl_xor(s, 16);
      s += __shfl_xor(s, 32);
      lreg[rb] = lreg[rb] * f + s;
      mreg[rb] = Mn;
      fx[rb] = f;
#pragma unroll
      for (int q = 0; q < 8; ++q) ph[rb][q] = (short)bf16_rne(pv[q]);
    }
    // ---- D: PV, 4 row-blocks share one V-tile (no barrier; regs only) ----
#pragma unroll
    for (int rb = 0; rb < 4; ++rb) {
      float fr[4];
#pragma unroll
      for (int r = 0; r < 4; ++r) fr[r] = __shfl(fx[rb], g * 4 + r);
#pragma unroll
      for (int nf = 0; nf < 4; ++nf) {
        f32x4 a = oacc[rb][nf];
#pragma unroll
        for (int r = 0; r < 4; ++r) a[r] *= fr[r];
        oacc[rb][nf] = mfma16(ph[rb], vhf[nf], a);
      }
    }
  }
  // ---- epilogue: (m,l) + unnormalized O ----
#pragma unroll
  for (int rb = 0; rb < 4; ++rb) {
    if (g == 0)
      ml[((size_t)sId * 16 + bh) * kN + (i0 + rb * 16 + col)] =
          make_float2(mreg[rb], lreg[rb]);
#pragma unroll
    for (int r = 0; r < 4; ++r) {
      float* dst = opart + ((size_t)bI * kN + i0 + rb * 16 + g * 4 + r) * 512 + h * 64;
#pragma unroll
      for (int nf = 0; nf < 4; ++nf)
        dst[nf * 16 + col] = oacc[rb][nf][r];
    }
  }
}

// ---------------- K3b: combine split partials in place into op0 ----------------
__global__ __launch_bounds__(256) void k_combine(float* __restrict__ op,
    const float2* __restrict__ ml, int S) {
  const size_t e = ((size_t)blockIdx.x * 256 + threadIdx.x) * 4;
  const int row = (int)(e >> 9);
  const int col = (int)(e & 511);
  const int h = col >> 6;
  const int bI = row >> 11;
  const int n = row & 2047;
  const size_t mlBase = (size_t)(bI * 8 + h) * kN + n;
  float ms = -INFINITY;
  for (int s = 0; s < S; ++s)
    ms = fmaxf(ms, ml[(size_t)s * 16 * kN + mlBase].x);
  float L = 0.f;
  float4 acc = make_float4(0.f, 0.f, 0.f, 0.f);
  for (int s = 0; s < S; ++s) {
    float2 v = ml[(size_t)s * 16 * kN + mlBase];
    float wgt = __expf(v.x - ms);
    L += v.y * wgt;
    float4 o4 = *(const float4*)(op + (size_t)s * OP_STRIDE + e);
    acc.x += o4.x * wgt; acc.y += o4.y * wgt;
    acc.z += o4.z * wgt; acc.w += o4.w * wgt;
  }
  float inv = 1.0f / L;
  *(float4*)(op + e) = make_float4(acc.x * inv, acc.y * inv,
                                   acc.z * inv, acc.w * inv);
}

// ---------------- K4: out projection via MFMA (hi/lo 3-term) + bias --------
__global__ __launch_bounds__(256, 3) void k_gemm_out(
    const float* __restrict__ a, const float* __restrict__ w,
    const float* __restrict__ bias, float* __restrict__ out) {
  __shared__ unsigned short Ah[128 * 40], Al[128 * 40];
  __shared__ unsigned short Bh[64 * 40], Bl[64 * 40];
  const int t = threadIdx.x;
  const int wv = t >> 6;
  const int lane = t & 63;
  const int col = lane & 15, gq = lane >> 4;
  const int n0 = blockIdx.x * 64;
  const int m0 = blockIdx.y * 128;
  const int ar = t >> 1, aq = (t & 1) * 16;
  const int bk = t >> 3, bn8 = (t & 7) * 8;
  const float* ap = a + (size_t)(m0 + ar) * 512;
  const float* wp = w + (size_t)bk * 512 + n0 + bn8;

  f32x4 acc[2][4];
#pragma unroll
  for (int am = 0; am < 2; ++am)
#pragma unroll
    for (int bn = 0; bn < 4; ++bn) acc[am][bn] = (f32x4){0.f, 0.f, 0.f, 0.f};

  for (int k0 = 0; k0 < 512; k0 += 32) {
#pragma unroll
    for (int half = 0; half < 2; ++half) {
      const int kk = k0 + aq + half * 8;
      float4 xa = *(const float4*)(ap + kk);
      float4 xb = *(const float4*)(ap + kk + 4);
      float e[8] = {xa.x, xa.y, xa.z, xa.w, xb.x, xb.y, xb.z, xb.w};
      u16x8 vh, vl;
#pragma unroll
      for (int i = 0; i < 8; ++i) {
        unsigned short hi2, lo2;
        bf16_split(e[i], hi2, lo2);
        vh[i] = hi2;
        vl[i] = lo2;
      }
      *(u16x8*)&Ah[ar * 40 + aq + half * 8] = vh;
      *(u16x8*)&Al[ar * 40 + aq + half * 8] = vl;
    }
    {
      float4 wa = *(const float4*)(wp + (size_t)k0 * 512);
      float4 wb = *(const float4*)(wp + (size_t)k0 * 512 + 4);
      float we[8] = {wa.x, wa.y, wa.z, wa.w, wb.x, wb.y, wb.z, wb.w};
#pragma unroll
      for (int i = 0; i < 8; ++i) {
        unsigned short hi2, lo2;
        bf16_split(we[i], hi2, lo2);
        Bh[(bn8 + i) * 40 + bk] = hi2;
        Bl[(bn8 + i) * 40 + bk] = lo2;
      }
    }
    __syncthreads();
    bf16x8 bhf[4], blf[4];
#pragma unroll
    for (int bn = 0; bn < 4; ++bn) {
      bhf[bn] = *(const bf16x8*)&Bh[(bn * 16 + col) * 40 + gq * 8];
      blf[bn] = *(const bf16x8*)&Bl[(bn * 16 + col) * 40 + gq * 8];
    }
#pragma unroll
    for (int am = 0; am < 2; ++am) {
      const int arow = wv * 32 + am * 16 + col;
      bf16x8 ahf = *(const bf16x8*)&Ah[arow * 40 + gq * 8];
      bf16x8 alf = *(const bf16x8*)&Al[arow * 40 + gq * 8];
#pragma unroll
      for (int bn = 0; bn < 4; ++bn) {
        f32x4 aa = acc[am][bn];
        aa = mfma16(ahf, bhf[bn], aa);
        aa = mfma16(alf, bhf[bn], aa);
        aa = mfma16(ahf, blf[bn], aa);
        acc[am][bn] = aa;
      }
    }
    __syncthreads();
  }
  float bv[4];
#pragma unroll
  for (int bn = 0; bn < 4; ++bn) bv[bn] = bias[n0 + bn * 16 + col];
#pragma unroll
  for (int am = 0; am < 2; ++am) {
#pragma unroll
    for (int r = 0; r < 4; ++r) {
      const int m = m0 + wv * 32 + am * 16 + gq * 4 + r;
#pragma unroll
      for (int bn = 0; bn < 4; ++bn)
        out[(size_t)m * 512 + n0 + bn * 16 + col] = acc[am][bn][r] + bv[bn];
    }
  }
}

extern "C" void kernel_launch(void* const* d_in, const int* in_sizes, int n_in,
                              void* d_out, int out_size, void* d_ws, size_t ws_size,
                              hipStream_t stream) {
  (void)in_sizes; (void)n_in; (void)out_size;
  const float* x    = (const float*)d_in[0];
  const float* sph  = (const float*)d_in[1];
  const float* g    = (const float*)d_in[2];
  const float* bta  = (const float*)d_in[3];
  const float* wqkv = (const float*)d_in[4];
  const float* wout = (const float*)d_in[5];
  const float* bout = (const float*)d_in[6];
  float* out = (float*)d_out;
  char* ws = (char*)d_ws;

  unsigned short* qhi  = (unsigned short*)(ws + OFF_QHI);
  unsigned short* qlo  = (unsigned short*)(ws + OFF_QLO);
  unsigned short* khi  = (unsigned short*)(ws + OFF_KHI);
  unsigned short* vthi = (unsigned short*)(ws + OFF_VTHI);
  unsigned short* vnhi = (unsigned short*)(ws + OFF_VNHI);
  float* op = (float*)(ws + OFF_OP);

  // split count by ws: need 20MB planes + S*(8MB + 256KB) + 64KB. Cap at 4.
  int S, jLen;
  if      (ws_size >= (54u << 20)) { S = 4; jLen = 512;  }
  else if (ws_size >= (46u << 20)) { S = 3; jLen = 704;  }
  else if (ws_size >= (37u << 20)) { S = 2; jLen = 1024; }
  else                             { S = 1; jLen = 2048; }
  float2* ml = (float2*)(ws + OFF_OP + (size_t)S * OP_STRIDE * 4);
  float* mu  = (float*)((char*)ml + (size_t)S * 16 * kN * 8);
  float* rs  = mu + 4096;

  k_ln_stats<<<dim3(1024), dim3(256), 0, stream>>>(x, mu, rs);
  k_gemm_qkv<<<dim3(24, 32), dim3(256), 0, stream>>>(x, mu, rs, g, bta, wqkv,
                                                     qhi, qlo, khi, vnhi);
  k_vtrans<<<dim3(512), dim3(256), 0, stream>>>(vnhi, vthi);
  k_attn<<<dim3(64 * S), dim3(512), 0, stream>>>(qhi, qlo, khi, vthi,
                                                 sph, op, ml, jLen);
  k_combine<<<dim3(2048), dim3(256), 0, stream>>>(op, ml, S);
  k_gemm_out<<<dim3(8, 32), dim3(256), 0, stream>>>(op, wout, bout, out);
}